// Round 3
// baseline (923.553 us; speedup 1.0000x reference)
//
#include <hip/hip_runtime.h>
#include <hip/hip_bf16.h>

// AWQ w4a16 GEMM + fused LoRA, MI355X (gfx950).
//   Xe  [8192][4160] bf16 = [ x (bf16) | t = x @ lora_a (bf16) ]
//   Wt  [11008][4160] bf16 = [ ((q - z) * s)^T | lora_b^T ]
//   out [8192][11008] f32 = Xe @ Wt^T     (K' = 4160, NT = 65 K-tiles of 64)
// GEMM: 256x256, 8 waves (2M x 4N), BK=64, 128 KiB LDS, 4 phases/K-tile.
// Deep prefetch: stages issued during tile t fill buf[t&1] with tile t+2,
// at quarter-region granularity so writes land only in regions whose reads
// for tile t already completed. Single counted vmcnt(8) per K-tile.

typedef __bf16 bf16x8 __attribute__((ext_vector_type(8)));
typedef float f32x4 __attribute__((ext_vector_type(4)));

#define GLOAD_LDS16(gp, lp)                                                    \
  __builtin_amdgcn_global_load_lds(                                            \
      (const __attribute__((address_space(1))) void*)(gp),                     \
      (__attribute__((address_space(3))) void*)(lp), 16, 0, 0)

#define SB0() __builtin_amdgcn_sched_barrier(0)
#define BAR() __builtin_amdgcn_s_barrier()

__device__ __forceinline__ unsigned short f2b(float f) {
  unsigned int u = __builtin_bit_cast(unsigned int, f);
  unsigned int r = u + 0x7fffu + ((u >> 16) & 1u);  // RTNE
  return (unsigned short)(r >> 16);
}

constexpr int M_DIM = 8192;
constexpr int K_DIM = 4096;
constexpr int N_DIM = 11008;
constexpr int R_DIM = 64;
constexpr int KP = K_DIM + R_DIM;  // 4160
constexpr int NT = KP / 64;        // 65 K-tiles

// ---------------------------------------------------------------- prep: t = x@A, plus x->bf16
// Each block: 16 rows. Stages x chunks in LDS for the rank-64 GEMM and writes
// the bf16 conversion of the same chunk straight from registers (fuses cvt_x).
__global__ __launch_bounds__(256) void prep_x_kernel(
    const float* __restrict__ x, const float* __restrict__ A,
    unsigned short* __restrict__ Xe) {
  __shared__ float xs[16][128];
  __shared__ float as[128][64];
  const int tid = threadIdx.x;
  const int r0 = blockIdx.x * 16;
  const int c = tid & 63;
  const int rg = tid >> 6;
  float acc[4] = {0.f, 0.f, 0.f, 0.f};
  for (int kc = 0; kc < K_DIM; kc += 128) {
    __syncthreads();
#pragma unroll
    for (int i = 0; i < 2; ++i) {
      const int flat = i * 1024 + tid * 4;
      const int row = flat >> 7, col = flat & 127;
      const float4 v = *(const float4*)(x + (size_t)(r0 + row) * K_DIM + kc + col);
      *(float4*)&xs[row][col] = v;
      unsigned short h[4] = {f2b(v.x), f2b(v.y), f2b(v.z), f2b(v.w)};
      *(uint2*)(Xe + (size_t)(r0 + row) * KP + kc + col) = *(const uint2*)h;
    }
#pragma unroll
    for (int j = 0; j < 8; ++j)
      ((float4*)as)[j * 256 + tid] =
          ((const float4*)(A + (size_t)kc * R_DIM))[j * 256 + tid];
    __syncthreads();
    for (int kk = 0; kk < 128; kk += 4) {
      float4 xv[4];
#pragma unroll
      for (int i = 0; i < 4; ++i) xv[i] = *(const float4*)&xs[rg * 4 + i][kk];
#pragma unroll
      for (int q = 0; q < 4; ++q) {
        const float b = as[kk + q][c];
        acc[0] += ((const float*)&xv[0])[q] * b;
        acc[1] += ((const float*)&xv[1])[q] * b;
        acc[2] += ((const float*)&xv[2])[q] * b;
        acc[3] += ((const float*)&xv[3])[q] * b;
      }
    }
  }
#pragma unroll
  for (int i = 0; i < 4; ++i)
    Xe[(size_t)(r0 + rg * 4 + i) * KP + K_DIM + c] = f2b(acc[i]);
}

// ---------------------------------------------------------------- prep: dequant + transpose
__global__ __launch_bounds__(256) void dequant_kernel(
    const int* __restrict__ qw, const int* __restrict__ qz,
    const float* __restrict__ sc, unsigned short* __restrict__ Wt) {
  __shared__ unsigned short w_lds[64][68];
  const int tid = threadIdx.x;
  const int n0 = blockIdx.x * 64, k0 = blockIdx.y * 64;
  const int g = k0 >> 7;
  const int nl = tid & 63;
  const int kl0 = tid >> 6;
  const int zv = qz[(size_t)g * N_DIM + n0 + nl];
  const float sv = sc[(size_t)g * N_DIM + n0 + nl];
#pragma unroll
  for (int i = 0; i < 16; ++i) {
    const int kl = i * 4 + kl0;
    const int q = qw[(size_t)(k0 + kl) * N_DIM + n0 + nl];
    w_lds[nl][kl] = f2b((float)(q - zv) * sv);
  }
  __syncthreads();
#pragma unroll
  for (int p = 0; p < 2; ++p) {
    const int chunk = p * 256 + tid;
    const int nr = chunk >> 3, k8 = chunk & 7;
    const unsigned short* rp = &w_lds[nr][k8 * 8];
    const uint2 lo = *(const uint2*)rp;
    const uint2 hi = *(const uint2*)(rp + 4);
    uint4 v;
    v.x = lo.x; v.y = lo.y; v.z = hi.x; v.w = hi.y;
    *(uint4*)(Wt + (size_t)(n0 + nr) * KP + k0 + k8 * 8) = v;
  }
}

// ---------------------------------------------------------------- prep: lora_b^T
__global__ __launch_bounds__(256) void lorab_t_kernel(
    const float* __restrict__ B, unsigned short* __restrict__ Wt) {
  __shared__ unsigned short b_lds[64][68];
  const int tid = threadIdx.x;
  const int n0 = blockIdx.x * 64;
  const int nl = tid & 63;
  const int rl0 = tid >> 6;
#pragma unroll
  for (int i = 0; i < 16; ++i) {
    const int rl = i * 4 + rl0;
    b_lds[nl][rl] = f2b(B[(size_t)rl * N_DIM + n0 + nl]);
  }
  __syncthreads();
#pragma unroll
  for (int p = 0; p < 2; ++p) {
    const int chunk = p * 256 + tid;
    const int nr = chunk >> 3, r8 = chunk & 7;
    const unsigned short* rp = &b_lds[nr][r8 * 8];
    const uint2 lo = *(const uint2*)rp;
    const uint2 hi = *(const uint2*)(rp + 4);
    uint4 v;
    v.x = lo.x; v.y = lo.y; v.z = hi.x; v.w = hi.y;
    *(uint4*)(Wt + (size_t)(n0 + nr) * KP + K_DIM + r8 * 8) = v;
  }
}

// ---------------------------------------------------------------- main GEMM (256^2, deep prefetch)
// LDS: [dbuf][op A/B][half][128*64] bf16 = 8 x 16 KiB regions.
// Region read points for tile t (buf b): A rows 0-63: P1. A rows 64-127: P3.
//   B[h] rows {0-31,64-95}: P1; rows {32-63,96-127}: P2.
// Stages during tile t fill buf b with tile t+2:
//   P2: A q0 (rows 0-63, both regions)     [A q0 dead after P1]
//   P3: B full (both regions)              [B dead after P2]
//   P4: A q1 (rows 64-127, both regions)   [A q1 dead after P3]
// vmcnt(8) at P4 end drains everything issued during tile t-1 (= tile t+1's
// data, 4-6 phase lead); vmcnt(0) when this tile issued no stages (tail).
__global__ __launch_bounds__(512, 2) void gemm_kernel(
    const unsigned short* __restrict__ Xe, const unsigned short* __restrict__ Wt,
    float* __restrict__ out) {
  __shared__ unsigned short lds[2][2][2][128 * 64];
  const int tid = threadIdx.x;
  const int w = tid >> 6, lane = tid & 63;
  // T1: bijective XCD swizzle, 1376 = 8 * 172
  const int orig = blockIdx.x;
  const int wg = (orig & 7) * 172 + (orig >> 3);
  const int bm = wg & 31;   // 32 M-tiles
  const int bn = wg >> 5;   // 43 N-tiles
  const int wr = w >> 2, wc = w & 3;

  // staging: row stripe per wave, pre-swizzled logical chunk (T2 source perm)
  const int rb = w * 8 + (lane >> 3);
  const int sc = ((lane & 7) ^ (lane >> 3)) * 8;
  const unsigned short* gA = Xe + (size_t)(bm * 256 + rb) * KP + sc;
  const unsigned short* gB = Wt + (size_t)(bn * 256 + rb) * KP + sc;

  // fragment read offsets (ushort units); chunk XOR on read side
  const int rowA = (lane & 15) * 64;
  const int rowB = ((wc & 1) * 64 + (lane & 15)) * 64;
  const int cx0 = (((lane >> 4) ^ (lane & 7))) * 8;
  const int cx1 = ((((lane >> 4) + 4) ^ (lane & 7))) * 8;

  f32x4 acc[8][4];
#pragma unroll
  for (int i = 0; i < 8; ++i)
#pragma unroll
    for (int j = 0; j < 4; ++j) acc[i][j] = (f32x4){0.f, 0.f, 0.f, 0.f};

  bf16x8 a[4][2], b0[2][2], b1[2][2];

  // one gload_lds: 64 rows (region-rows [rq*64, rq*64+64)) of region [op][half]
  auto stage1 = [&](const unsigned short* g, int buf, int op, int half, int rq,
                    int kt) {
    const unsigned short* s = g + (size_t)(half * 128 + rq * 64) * KP + kt * 64;
    unsigned short* d = &lds[buf][op][half][rq * 4096 + w * 512];
    GLOAD_LDS16(s, d);
  };

#define LDA(buf, mh)                                                           \
  do {                                                                         \
    const unsigned short* R = &lds[buf][0][wr][0];                             \
    _Pragma("unroll") for (int i = 0; i < 4; ++i) {                            \
      a[i][0] = *(const bf16x8*)(R + ((mh)*4 + i) * 1024 + rowA + cx0);        \
      a[i][1] = *(const bf16x8*)(R + ((mh)*4 + i) * 1024 + rowA + cx1);        \
    }                                                                          \
  } while (0)

#define LDB(buf, dst, nh)                                                      \
  do {                                                                         \
    const unsigned short* R = &lds[buf][1][wc >> 1][0];                        \
    _Pragma("unroll") for (int j = 0; j < 2; ++j) {                            \
      dst[j][0] = *(const bf16x8*)(R + ((nh)*2 + j) * 1024 + rowB + cx0);      \
      dst[j][1] = *(const bf16x8*)(R + ((nh)*2 + j) * 1024 + rowB + cx1);      \
    }                                                                          \
  } while (0)

#define MFMAQ(mh, bb, nh)                                                      \
  do {                                                                         \
    _Pragma("unroll") for (int ks = 0; ks < 2; ++ks)                           \
    _Pragma("unroll") for (int i = 0; i < 4; ++i)                              \
    _Pragma("unroll") for (int j = 0; j < 2; ++j)                              \
      acc[(mh)*4 + i][(nh)*2 + j] = __builtin_amdgcn_mfma_f32_16x16x32_bf16(   \
          a[i][ks], bb[j][ks], acc[(mh)*4 + i][(nh)*2 + j], 0, 0, 0);          \
  } while (0)

#define PHASE_SYNC_IN()  do { SB0(); BAR(); SB0(); } while (0)
#define PRIO_ON()  do { __builtin_amdgcn_s_setprio(1); SB0(); } while (0)
#define PRIO_OFF() do { SB0(); __builtin_amdgcn_s_setprio(0); } while (0)

  // prologue: tiles 0 and 1 fully staged (8 loads each)
#pragma unroll
  for (int t = 0; t < 2; ++t) {
    stage1(gA, t, 0, 0, 0, t); stage1(gA, t, 0, 1, 0, t);
    stage1(gA, t, 0, 0, 1, t); stage1(gA, t, 0, 1, 1, t);
    stage1(gB, t, 1, 0, 0, t); stage1(gB, t, 1, 0, 1, t);
    stage1(gB, t, 1, 1, 0, t); stage1(gB, t, 1, 1, 1, t);
  }
  asm volatile("s_waitcnt vmcnt(8)" ::: "memory");  // tile0 landed, tile1 in flight
  PHASE_SYNC_IN();

  for (int kt = 0; kt < NT; ++kt) {
    const int buf = kt & 1;
    const bool s2 = kt + 2 < NT;
    const int kt2 = kt + 2;
    // ---- P1: reads only
    LDA(buf, 0);
    LDB(buf, b0, 0);
    PHASE_SYNC_IN();
    PRIO_ON();  MFMAQ(0, b0, 0);  PRIO_OFF();
    PHASE_SYNC_IN();
    // ---- P2: stage A q0 of t+2 (A rows 0-63 dead after P1)
    LDB(buf, b1, 1);
    if (s2) { stage1(gA, buf, 0, 0, 0, kt2); stage1(gA, buf, 0, 1, 0, kt2); }
    PHASE_SYNC_IN();
    PRIO_ON();  MFMAQ(0, b1, 1);  PRIO_OFF();
    PHASE_SYNC_IN();
    // ---- P3: stage B full of t+2 (B dead after P2)
    LDA(buf, 1);
    if (s2) {
      stage1(gB, buf, 1, 0, 0, kt2); stage1(gB, buf, 1, 0, 1, kt2);
      stage1(gB, buf, 1, 1, 0, kt2); stage1(gB, buf, 1, 1, 1, kt2);
    }
    PHASE_SYNC_IN();
    PRIO_ON();  MFMAQ(1, b1, 1);  PRIO_OFF();
    PHASE_SYNC_IN();
    // ---- P4: stage A q1 of t+2 (A rows 64-127 dead after P3)
    if (s2) { stage1(gA, buf, 0, 0, 1, kt2); stage1(gA, buf, 0, 1, 1, kt2); }
    PHASE_SYNC_IN();
    PRIO_ON();  MFMAQ(1, b0, 0);  PRIO_OFF();
    SB0();
    if (s2) { asm volatile("s_waitcnt vmcnt(8)" ::: "memory"); }
    else    { asm volatile("s_waitcnt vmcnt(0)" ::: "memory"); }
    PHASE_SYNC_IN();
  }

  // epilogue: C/D layout col=lane&15, row=(lane>>4)*4+jj
  const int orow = bm * 256 + wr * 128 + ((lane >> 4) << 2);
  const int ocol = bn * 256 + wc * 64 + (lane & 15);
#pragma unroll
  for (int mf = 0; mf < 8; ++mf)
#pragma unroll
    for (int nf = 0; nf < 4; ++nf)
#pragma unroll
      for (int jj = 0; jj < 4; ++jj)
        out[(size_t)(orow + mf * 16 + jj) * N_DIM + ocol + nf * 16] =
            acc[mf][nf][jj];
}

// ---------------------------------------------------------------- launch
extern "C" void kernel_launch(void* const* d_in, const int* in_sizes, int n_in,
                              void* d_out, int out_size, void* d_ws, size_t ws_size,
                              hipStream_t stream) {
  const float* x = (const float*)d_in[0];
  const float* scales = (const float*)d_in[1];
  const float* lora_a = (const float*)d_in[2];
  const float* lora_b = (const float*)d_in[3];
  const int* qweight = (const int*)d_in[4];
  const int* qzeros = (const int*)d_in[5];
  float* out = (float*)d_out;

  unsigned short* Xe = (unsigned short*)d_ws;
  unsigned short* Wt = Xe + (size_t)M_DIM * KP;

  prep_x_kernel<<<M_DIM / 16, 256, 0, stream>>>(x, lora_a, Xe);
  dequant_kernel<<<dim3(N_DIM / 64, K_DIM / 64), 256, 0, stream>>>(qweight, qzeros,
                                                                   scales, Wt);
  lorab_t_kernel<<<N_DIM / 64, 256, 0, stream>>>(lora_b, Wt);
  gemm_kernel<<<dim3((N_DIM / 256) * (M_DIM / 256)), 512, 0, stream>>>(Xe, Wt, out);
}

// Round 4
// 874.193 us; speedup vs baseline: 1.0565x; 1.0565x over previous
//
#include <hip/hip_runtime.h>
#include <hip/hip_bf16.h>

// AWQ w4a16 GEMM + fused LoRA, MI355X (gfx950).
//   Xe  [8192][4160] bf16 = [ x (bf16) | t = x @ lora_a (bf16) ]
//   Wt  [11008][4160] bf16 = [ ((q - z) * s)^T | lora_b^T ]
//   out [8192][11008] f32 = Xe @ Wt^T     (K' = 4160, NT = 65 K-tiles of 64)
// GEMM: 256x256, 8 waves (2M x 4N), BK=64, 128 KiB LDS, 4 phases/K-tile,
// even 2-gload staging per phase (A(t+1) at P1/P2, B(t+2) at P3/P4),
// single counted vmcnt(4) per K-tile, x2 unrolled (compile-time buf),
// m201-style sync: lgkmcnt(0)+sched_barrier after pre-MFMA barrier,
// lgkmcnt(8) pacing at the 12-read phase, setprio around MFMA clusters.

typedef __bf16 bf16x8 __attribute__((ext_vector_type(8)));
typedef float f32x4 __attribute__((ext_vector_type(4)));

#define GLOAD_LDS16(gp, lp)                                                    \
  __builtin_amdgcn_global_load_lds(                                            \
      (const __attribute__((address_space(1))) void*)(gp),                     \
      (__attribute__((address_space(3))) void*)(lp), 16, 0, 0)

#define SB0() __builtin_amdgcn_sched_barrier(0)
#define BAR() __builtin_amdgcn_s_barrier()

__device__ __forceinline__ unsigned short f2b(float f) {
  unsigned int u = __builtin_bit_cast(unsigned int, f);
  unsigned int r = u + 0x7fffu + ((u >> 16) & 1u);  // RTNE
  return (unsigned short)(r >> 16);
}

constexpr int M_DIM = 8192;
constexpr int K_DIM = 4096;
constexpr int N_DIM = 11008;
constexpr int R_DIM = 64;
constexpr int KP = K_DIM + R_DIM;  // 4160
constexpr int NT = KP / 64;        // 65 K-tiles

// ---------------------------------------------------------------- prep: t = x@A, plus x->bf16
__global__ __launch_bounds__(256) void prep_x_kernel(
    const float* __restrict__ x, const float* __restrict__ A,
    unsigned short* __restrict__ Xe) {
  __shared__ float xs[16][128];
  __shared__ float as[128][64];
  const int tid = threadIdx.x;
  const int r0 = blockIdx.x * 16;
  const int c = tid & 63;
  const int rg = tid >> 6;
  float acc[4] = {0.f, 0.f, 0.f, 0.f};
  for (int kc = 0; kc < K_DIM; kc += 128) {
    __syncthreads();
#pragma unroll
    for (int i = 0; i < 2; ++i) {
      const int flat = i * 1024 + tid * 4;
      const int row = flat >> 7, col = flat & 127;
      const float4 v = *(const float4*)(x + (size_t)(r0 + row) * K_DIM + kc + col);
      *(float4*)&xs[row][col] = v;
      unsigned short h[4] = {f2b(v.x), f2b(v.y), f2b(v.z), f2b(v.w)};
      *(uint2*)(Xe + (size_t)(r0 + row) * KP + kc + col) = *(const uint2*)h;
    }
#pragma unroll
    for (int j = 0; j < 8; ++j)
      ((float4*)as)[j * 256 + tid] =
          ((const float4*)(A + (size_t)kc * R_DIM))[j * 256 + tid];
    __syncthreads();
    for (int kk = 0; kk < 128; kk += 4) {
      float4 xv[4];
#pragma unroll
      for (int i = 0; i < 4; ++i) xv[i] = *(const float4*)&xs[rg * 4 + i][kk];
#pragma unroll
      for (int q = 0; q < 4; ++q) {
        const float b = as[kk + q][c];
        acc[0] += ((const float*)&xv[0])[q] * b;
        acc[1] += ((const float*)&xv[1])[q] * b;
        acc[2] += ((const float*)&xv[2])[q] * b;
        acc[3] += ((const float*)&xv[3])[q] * b;
      }
    }
  }
#pragma unroll
  for (int i = 0; i < 4; ++i)
    Xe[(size_t)(r0 + rg * 4 + i) * KP + K_DIM + c] = f2b(acc[i]);
}

// ---------------------------------------------------------------- prep: dequant + transpose
__global__ __launch_bounds__(256) void dequant_kernel(
    const int* __restrict__ qw, const int* __restrict__ qz,
    const float* __restrict__ sc, unsigned short* __restrict__ Wt) {
  __shared__ unsigned short w_lds[64][68];
  const int tid = threadIdx.x;
  const int n0 = blockIdx.x * 64, k0 = blockIdx.y * 64;
  const int g = k0 >> 7;
  const int nl = tid & 63;
  const int kl0 = tid >> 6;
  const int zv = qz[(size_t)g * N_DIM + n0 + nl];
  const float sv = sc[(size_t)g * N_DIM + n0 + nl];
#pragma unroll
  for (int i = 0; i < 16; ++i) {
    const int kl = i * 4 + kl0;
    const int q = qw[(size_t)(k0 + kl) * N_DIM + n0 + nl];
    w_lds[nl][kl] = f2b((float)(q - zv) * sv);
  }
  __syncthreads();
#pragma unroll
  for (int p = 0; p < 2; ++p) {
    const int chunk = p * 256 + tid;
    const int nr = chunk >> 3, k8 = chunk & 7;
    const unsigned short* rp = &w_lds[nr][k8 * 8];
    const uint2 lo = *(const uint2*)rp;
    const uint2 hi = *(const uint2*)(rp + 4);
    uint4 v;
    v.x = lo.x; v.y = lo.y; v.z = hi.x; v.w = hi.y;
    *(uint4*)(Wt + (size_t)(n0 + nr) * KP + k0 + k8 * 8) = v;
  }
}

// ---------------------------------------------------------------- prep: lora_b^T
__global__ __launch_bounds__(256) void lorab_t_kernel(
    const float* __restrict__ B, unsigned short* __restrict__ Wt) {
  __shared__ unsigned short b_lds[64][68];
  const int tid = threadIdx.x;
  const int n0 = blockIdx.x * 64;
  const int nl = tid & 63;
  const int rl0 = tid >> 6;
#pragma unroll
  for (int i = 0; i < 16; ++i) {
    const int rl = i * 4 + rl0;
    b_lds[nl][rl] = f2b(B[(size_t)rl * N_DIM + n0 + nl]);
  }
  __syncthreads();
#pragma unroll
  for (int p = 0; p < 2; ++p) {
    const int chunk = p * 256 + tid;
    const int nr = chunk >> 3, r8 = chunk & 7;
    const unsigned short* rp = &b_lds[nr][r8 * 8];
    const uint2 lo = *(const uint2*)rp;
    const uint2 hi = *(const uint2*)(rp + 4);
    uint4 v;
    v.x = lo.x; v.y = lo.y; v.z = hi.x; v.w = hi.y;
    *(uint4*)(Wt + (size_t)(n0 + nr) * KP + K_DIM + r8 * 8) = v;
  }
}

// ---------------------------------------------------------------- main GEMM
__global__ __launch_bounds__(512, 2) void gemm_kernel(
    const unsigned short* __restrict__ Xe, const unsigned short* __restrict__ Wt,
    float* __restrict__ out) {
  __shared__ unsigned short lds[2][2][2][128 * 64];
  const int tid = threadIdx.x;
  const int w = tid >> 6, lane = tid & 63;
  // T1: bijective XCD swizzle, 1376 = 8 * 172
  const int orig = blockIdx.x;
  const int wg = (orig & 7) * 172 + (orig >> 3);
  const int bm = wg & 31;   // 32 M-tiles
  const int bn = wg >> 5;   // 43 N-tiles
  const int wr = w >> 2, wc = w & 3;

  // staging: row stripe per wave, pre-swizzled logical chunk (T2 source perm)
  const int rb = w * 8 + (lane >> 3);
  const int sc = ((lane & 7) ^ (lane >> 3)) * 8;
  const unsigned short* gA = Xe + (size_t)(bm * 256 + rb) * KP + sc;
  const unsigned short* gB = Wt + (size_t)(bn * 256 + rb) * KP + sc;

  // fragment read offsets (ushort units); chunk XOR on read side
  const int rowA = (lane & 15) * 64;
  const int rowB = ((wc & 1) * 64 + (lane & 15)) * 64;
  const int cx0 = (((lane >> 4) ^ (lane & 7))) * 8;
  const int cx1 = ((((lane >> 4) + 4) ^ (lane & 7))) * 8;

  f32x4 acc[8][4];
#pragma unroll
  for (int i = 0; i < 8; ++i)
#pragma unroll
    for (int j = 0; j < 4; ++j) acc[i][j] = (f32x4){0.f, 0.f, 0.f, 0.f};

  bf16x8 a[4][2], b0[2][2], b1[2][2];

  // one gload_lds: rows [rq*64, rq*64+64) of region [op][half]
  auto stage1 = [&](const unsigned short* g, int buf, int op, int half, int rq,
                    int kt) {
    const unsigned short* s = g + (size_t)(half * 128 + rq * 64) * KP + kt * 64;
    unsigned short* d = &lds[buf][op][half][rq * 4096 + w * 512];
    GLOAD_LDS16(s, d);
  };

#define LDA(BUF, mh)                                                           \
  do {                                                                         \
    const unsigned short* R = &lds[BUF][0][wr][0];                             \
    _Pragma("unroll") for (int i = 0; i < 4; ++i) {                            \
      a[i][0] = *(const bf16x8*)(R + ((mh)*4 + i) * 1024 + rowA + cx0);        \
      a[i][1] = *(const bf16x8*)(R + ((mh)*4 + i) * 1024 + rowA + cx1);        \
    }                                                                          \
  } while (0)

#define LDB(BUF, dst, nh)                                                      \
  do {                                                                         \
    const unsigned short* R = &lds[BUF][1][wc >> 1][0];                        \
    _Pragma("unroll") for (int j = 0; j < 2; ++j) {                            \
      dst[j][0] = *(const bf16x8*)(R + ((nh)*2 + j) * 1024 + rowB + cx0);      \
      dst[j][1] = *(const bf16x8*)(R + ((nh)*2 + j) * 1024 + rowB + cx1);      \
    }                                                                          \
  } while (0)

#define MFMAQ(mh, bb, nh)                                                      \
  do {                                                                         \
    _Pragma("unroll") for (int ks = 0; ks < 2; ++ks)                           \
    _Pragma("unroll") for (int i = 0; i < 4; ++i)                              \
    _Pragma("unroll") for (int j = 0; j < 2; ++j)                              \
      acc[(mh)*4 + i][(nh)*2 + j] = __builtin_amdgcn_mfma_f32_16x16x32_bf16(   \
          a[i][ks], bb[j][ks], acc[(mh)*4 + i][(nh)*2 + j], 0, 0, 0);          \
  } while (0)

#define LGKM0() do { asm volatile("s_waitcnt lgkmcnt(0)" ::: "memory"); SB0(); } while (0)
#define PRIO_ON()  do { __builtin_amdgcn_s_setprio(1); SB0(); } while (0)
#define PRIO_OFF() do { SB0(); __builtin_amdgcn_s_setprio(0); } while (0)

// One K-tile, 4 phases. BUF compile-time. Staging: A(kt+1)->BUF^1 at P1/P2,
// B(kt+2)->BUF at P3/P4 (B regions of BUF dead after P2). vmcnt(4) at P4 end
// leaves B(kt+2) in flight, forces A(kt+1)+B(kt+1) landed.
#define TILE(KT, BUF, S1, S2)                                                  \
  do {                                                                         \
    const int kt_ = (KT);                                                      \
    /* P1 */                                                                   \
    LDA(BUF, 0);                                                               \
    LDB(BUF, b0, 0);                                                           \
    if (S1) { stage1(gA, (BUF) ^ 1, 0, 0, 0, kt_ + 1);                         \
              stage1(gA, (BUF) ^ 1, 0, 0, 1, kt_ + 1); }                       \
    asm volatile("s_waitcnt lgkmcnt(8)" ::: "memory");                         \
    SB0(); BAR(); SB0();                                                       \
    LGKM0();                                                                   \
    PRIO_ON(); MFMAQ(0, b0, 0); PRIO_OFF();                                    \
    SB0(); BAR(); SB0();                                                       \
    /* P2 */                                                                   \
    LDB(BUF, b1, 1);                                                           \
    if (S1) { stage1(gA, (BUF) ^ 1, 0, 1, 0, kt_ + 1);                         \
              stage1(gA, (BUF) ^ 1, 0, 1, 1, kt_ + 1); }                       \
    SB0(); BAR(); SB0();                                                       \
    LGKM0();                                                                   \
    PRIO_ON(); MFMAQ(0, b1, 1); PRIO_OFF();                                    \
    SB0(); BAR(); SB0();                                                       \
    /* P3 */                                                                   \
    LDA(BUF, 1);                                                               \
    if (S2) { stage1(gB, (BUF), 1, 0, 0, kt_ + 2);                             \
              stage1(gB, (BUF), 1, 0, 1, kt_ + 2); }                           \
    SB0(); BAR(); SB0();                                                       \
    LGKM0();                                                                   \
    PRIO_ON(); MFMAQ(1, b1, 1); PRIO_OFF();                                    \
    SB0(); BAR(); SB0();                                                       \
    /* P4 */                                                                   \
    if (S2) { stage1(gB, (BUF), 1, 1, 0, kt_ + 2);                             \
              stage1(gB, (BUF), 1, 1, 1, kt_ + 2); }                           \
    SB0(); BAR(); SB0();                                                       \
    PRIO_ON(); MFMAQ(1, b0, 0); PRIO_OFF();                                    \
    SB0();                                                                     \
    if (S2) { asm volatile("s_waitcnt vmcnt(4)" ::: "memory"); }               \
    else    { asm volatile("s_waitcnt vmcnt(0)" ::: "memory"); }               \
    SB0(); BAR(); SB0();                                                       \
  } while (0)

  // prologue: tile0 A+B (8 loads), tile1 B (4 loads); vmcnt(4) drains tile0.
  stage1(gA, 0, 0, 0, 0, 0); stage1(gA, 0, 0, 0, 1, 0);
  stage1(gA, 0, 0, 1, 0, 0); stage1(gA, 0, 0, 1, 1, 0);
  stage1(gB, 0, 1, 0, 0, 0); stage1(gB, 0, 1, 0, 1, 0);
  stage1(gB, 0, 1, 1, 0, 0); stage1(gB, 0, 1, 1, 1, 0);
  stage1(gB, 1, 1, 0, 0, 1); stage1(gB, 1, 1, 0, 1, 1);
  stage1(gB, 1, 1, 1, 0, 1); stage1(gB, 1, 1, 1, 1, 1);
  asm volatile("s_waitcnt vmcnt(4)" ::: "memory");
  SB0(); BAR(); SB0();

#pragma unroll 1
  for (int kt = 0; kt < 64; kt += 2) {
    TILE(kt, 0, true, true);
    TILE(kt + 1, 1, true, (kt < 62));
  }
  TILE(64, 0, false, false);

  // epilogue: C/D layout col=lane&15, row=(lane>>4)*4+jj
  const int orow = bm * 256 + wr * 128 + ((lane >> 4) << 2);
  const int ocol = bn * 256 + wc * 64 + (lane & 15);
#pragma unroll
  for (int mf = 0; mf < 8; ++mf)
#pragma unroll
    for (int nf = 0; nf < 4; ++nf)
#pragma unroll
      for (int jj = 0; jj < 4; ++jj)
        out[(size_t)(orow + mf * 16 + jj) * N_DIM + ocol + nf * 16] =
            acc[mf][nf][jj];
}

// ---------------------------------------------------------------- launch
extern "C" void kernel_launch(void* const* d_in, const int* in_sizes, int n_in,
                              void* d_out, int out_size, void* d_ws, size_t ws_size,
                              hipStream_t stream) {
  const float* x = (const float*)d_in[0];
  const float* scales = (const float*)d_in[1];
  const float* lora_a = (const float*)d_in[2];
  const float* lora_b = (const float*)d_in[3];
  const int* qweight = (const int*)d_in[4];
  const int* qzeros = (const int*)d_in[5];
  float* out = (float*)d_out;

  unsigned short* Xe = (unsigned short*)d_ws;
  unsigned short* Wt = Xe + (size_t)M_DIM * KP;

  prep_x_kernel<<<M_DIM / 16, 256, 0, stream>>>(x, lora_a, Xe);
  dequant_kernel<<<dim3(N_DIM / 64, K_DIM / 64), 256, 0, stream>>>(qweight, qzeros,
                                                                   scales, Wt);
  lorab_t_kernel<<<N_DIM / 64, 256, 0, stream>>>(lora_b, Wt);
  gemm_kernel<<<dim3((N_DIM / 256) * (M_DIM / 256)), 512, 0, stream>>>(Xe, Wt, out);
}

// Round 5
// 862.320 us; speedup vs baseline: 1.0710x; 1.0138x over previous
//
#include <hip/hip_runtime.h>
#include <hip/hip_bf16.h>

// AWQ w4a16 GEMM + fused LoRA, MI355X (gfx950).
//   Xe  [8192][4160] bf16 = [ x (bf16) | t = x @ lora_a (bf16) ]
//   Wt  [11008][4160] bf16 = [ ((q - z) * s)^T | lora_b^T ]
//   out [8192][11008] f32 = Xe @ Wt^T     (K' = 4160, NT = 65 K-tiles of 64)
// GEMM: 256x256, 8 waves (2M x 4N), BK=64, 128 KiB LDS, 4 phases/K-tile.
// Phase reads balanced 8/4/8/4: B(n0) fragments of tile t+1 are preloaded at
// P4 of tile t (register dbuf b0x/b0y). Stage A(t+1) at P1/P2, B(t+2) at
// P3/P4. Counted vmcnt(6) end-P3 (guarantees B(t+1) for the preload),
// vmcnt(4) end-P4 (guarantees A(t+1) for next P1). Never 0 until tail.

typedef __bf16 bf16x8 __attribute__((ext_vector_type(8)));
typedef float f32x4 __attribute__((ext_vector_type(4)));

#define GLOAD_LDS16(gp, lp)                                                    \
  __builtin_amdgcn_global_load_lds(                                            \
      (const __attribute__((address_space(1))) void*)(gp),                     \
      (__attribute__((address_space(3))) void*)(lp), 16, 0, 0)

#define SB0() __builtin_amdgcn_sched_barrier(0)
#define BAR() __builtin_amdgcn_s_barrier()

__device__ __forceinline__ unsigned short f2b(float f) {
  unsigned int u = __builtin_bit_cast(unsigned int, f);
  unsigned int r = u + 0x7fffu + ((u >> 16) & 1u);  // RTNE
  return (unsigned short)(r >> 16);
}

constexpr int M_DIM = 8192;
constexpr int K_DIM = 4096;
constexpr int N_DIM = 11008;
constexpr int R_DIM = 64;
constexpr int KP = K_DIM + R_DIM;  // 4160
constexpr int NT = KP / 64;        // 65 K-tiles

// ---------------------------------------------------------------- prep: t = x@A, plus x->bf16
__global__ __launch_bounds__(256) void prep_x_kernel(
    const float* __restrict__ x, const float* __restrict__ A,
    unsigned short* __restrict__ Xe) {
  __shared__ float xs[16][128];
  __shared__ float as[128][64];
  const int tid = threadIdx.x;
  const int r0 = blockIdx.x * 16;
  const int c = tid & 63;
  const int rg = tid >> 6;
  float acc[4] = {0.f, 0.f, 0.f, 0.f};
  for (int kc = 0; kc < K_DIM; kc += 128) {
    __syncthreads();
#pragma unroll
    for (int i = 0; i < 2; ++i) {
      const int flat = i * 1024 + tid * 4;
      const int row = flat >> 7, col = flat & 127;
      const float4 v = *(const float4*)(x + (size_t)(r0 + row) * K_DIM + kc + col);
      *(float4*)&xs[row][col] = v;
      unsigned short h[4] = {f2b(v.x), f2b(v.y), f2b(v.z), f2b(v.w)};
      *(uint2*)(Xe + (size_t)(r0 + row) * KP + kc + col) = *(const uint2*)h;
    }
#pragma unroll
    for (int j = 0; j < 8; ++j)
      ((float4*)as)[j * 256 + tid] =
          ((const float4*)(A + (size_t)kc * R_DIM))[j * 256 + tid];
    __syncthreads();
    for (int kk = 0; kk < 128; kk += 4) {
      float4 xv[4];
#pragma unroll
      for (int i = 0; i < 4; ++i) xv[i] = *(const float4*)&xs[rg * 4 + i][kk];
#pragma unroll
      for (int q = 0; q < 4; ++q) {
        const float b = as[kk + q][c];
        acc[0] += ((const float*)&xv[0])[q] * b;
        acc[1] += ((const float*)&xv[1])[q] * b;
        acc[2] += ((const float*)&xv[2])[q] * b;
        acc[3] += ((const float*)&xv[3])[q] * b;
      }
    }
  }
#pragma unroll
  for (int i = 0; i < 4; ++i)
    Xe[(size_t)(r0 + rg * 4 + i) * KP + K_DIM + c] = f2b(acc[i]);
}

// ---------------------------------------------------------------- prep: dequant + transpose
__global__ __launch_bounds__(256) void dequant_kernel(
    const int* __restrict__ qw, const int* __restrict__ qz,
    const float* __restrict__ sc, unsigned short* __restrict__ Wt) {
  __shared__ unsigned short w_lds[64][68];
  const int tid = threadIdx.x;
  const int n0 = blockIdx.x * 64, k0 = blockIdx.y * 64;
  const int g = k0 >> 7;
  const int nl = tid & 63;
  const int kl0 = tid >> 6;
  const int zv = qz[(size_t)g * N_DIM + n0 + nl];
  const float sv = sc[(size_t)g * N_DIM + n0 + nl];
#pragma unroll
  for (int i = 0; i < 16; ++i) {
    const int kl = i * 4 + kl0;
    const int q = qw[(size_t)(k0 + kl) * N_DIM + n0 + nl];
    w_lds[nl][kl] = f2b((float)(q - zv) * sv);
  }
  __syncthreads();
#pragma unroll
  for (int p = 0; p < 2; ++p) {
    const int chunk = p * 256 + tid;
    const int nr = chunk >> 3, k8 = chunk & 7;
    const unsigned short* rp = &w_lds[nr][k8 * 8];
    const uint2 lo = *(const uint2*)rp;
    const uint2 hi = *(const uint2*)(rp + 4);
    uint4 v;
    v.x = lo.x; v.y = lo.y; v.z = hi.x; v.w = hi.y;
    *(uint4*)(Wt + (size_t)(n0 + nr) * KP + k0 + k8 * 8) = v;
  }
}

// ---------------------------------------------------------------- prep: lora_b^T
__global__ __launch_bounds__(256) void lorab_t_kernel(
    const float* __restrict__ B, unsigned short* __restrict__ Wt) {
  __shared__ unsigned short b_lds[64][68];
  const int tid = threadIdx.x;
  const int n0 = blockIdx.x * 64;
  const int nl = tid & 63;
  const int rl0 = tid >> 6;
#pragma unroll
  for (int i = 0; i < 16; ++i) {
    const int rl = i * 4 + rl0;
    b_lds[nl][rl] = f2b(B[(size_t)rl * N_DIM + n0 + nl]);
  }
  __syncthreads();
#pragma unroll
  for (int p = 0; p < 2; ++p) {
    const int chunk = p * 256 + tid;
    const int nr = chunk >> 3, r8 = chunk & 7;
    const unsigned short* rp = &b_lds[nr][r8 * 8];
    const uint2 lo = *(const uint2*)rp;
    const uint2 hi = *(const uint2*)(rp + 4);
    uint4 v;
    v.x = lo.x; v.y = lo.y; v.z = hi.x; v.w = hi.y;
    *(uint4*)(Wt + (size_t)(n0 + nr) * KP + K_DIM + r8 * 8) = v;
  }
}

// ---------------------------------------------------------------- main GEMM
__global__ __launch_bounds__(512, 2) void gemm_kernel(
    const unsigned short* __restrict__ Xe, const unsigned short* __restrict__ Wt,
    float* __restrict__ out) {
  __shared__ unsigned short lds[2][2][2][128 * 64];
  const int tid = threadIdx.x;
  const int w = tid >> 6, lane = tid & 63;
  // T1: bijective XCD swizzle, 1376 = 8 * 172
  const int orig = blockIdx.x;
  const int wg = (orig & 7) * 172 + (orig >> 3);
  const int bm = wg & 31;   // 32 M-tiles
  const int bn = wg >> 5;   // 43 N-tiles
  const int wr = w >> 2, wc = w & 3;

  // staging: row stripe per wave, pre-swizzled logical chunk (T2 source perm)
  const int rb = w * 8 + (lane >> 3);
  const int sc = ((lane & 7) ^ (lane >> 3)) * 8;
  const unsigned short* gA = Xe + (size_t)(bm * 256 + rb) * KP + sc;
  const unsigned short* gB = Wt + (size_t)(bn * 256 + rb) * KP + sc;

  // fragment read offsets (ushort units); chunk XOR on read side
  const int rowA = (lane & 15) * 64;
  const int rowB = ((wc & 1) * 64 + (lane & 15)) * 64;
  const int cx0 = (((lane >> 4) ^ (lane & 7))) * 8;
  const int cx1 = ((((lane >> 4) + 4) ^ (lane & 7))) * 8;

  f32x4 acc[8][4];
#pragma unroll
  for (int i = 0; i < 8; ++i)
#pragma unroll
    for (int j = 0; j < 4; ++j) acc[i][j] = (f32x4){0.f, 0.f, 0.f, 0.f};

  bf16x8 a[4][2], b0x[2][2], b0y[2][2], b1[2][2];

  // one gload_lds: rows [rq*64, rq*64+64) of region [op][half]
  auto stage1 = [&](const unsigned short* g, int buf, int op, int half, int rq,
                    int kt) {
    const unsigned short* s = g + (size_t)(half * 128 + rq * 64) * KP + kt * 64;
    unsigned short* d = &lds[buf][op][half][rq * 4096 + w * 512];
    GLOAD_LDS16(s, d);
  };

#define LDA(BUF, mh)                                                           \
  do {                                                                         \
    const unsigned short* R = &lds[BUF][0][wr][0];                             \
    _Pragma("unroll") for (int i = 0; i < 4; ++i) {                            \
      a[i][0] = *(const bf16x8*)(R + ((mh)*4 + i) * 1024 + rowA + cx0);        \
      a[i][1] = *(const bf16x8*)(R + ((mh)*4 + i) * 1024 + rowA + cx1);        \
    }                                                                          \
  } while (0)

#define LDB(BUF, dst, nh)                                                      \
  do {                                                                         \
    const unsigned short* R = &lds[BUF][1][wc >> 1][0];                        \
    _Pragma("unroll") for (int j = 0; j < 2; ++j) {                            \
      dst[j][0] = *(const bf16x8*)(R + ((nh)*2 + j) * 1024 + rowB + cx0);      \
      dst[j][1] = *(const bf16x8*)(R + ((nh)*2 + j) * 1024 + rowB + cx1);      \
    }                                                                          \
  } while (0)

#define MFMAQ(mh, bb, nh)                                                      \
  do {                                                                         \
    _Pragma("unroll") for (int ks = 0; ks < 2; ++ks)                           \
    _Pragma("unroll") for (int i = 0; i < 4; ++i)                              \
    _Pragma("unroll") for (int j = 0; j < 2; ++j)                              \
      acc[(mh)*4 + i][(nh)*2 + j] = __builtin_amdgcn_mfma_f32_16x16x32_bf16(   \
          a[i][ks], bb[j][ks], acc[(mh)*4 + i][(nh)*2 + j], 0, 0, 0);          \
  } while (0)

#define LGKM0() do { asm volatile("s_waitcnt lgkmcnt(0)" ::: "memory"); SB0(); } while (0)
#define PRIO_ON()  do { __builtin_amdgcn_s_setprio(1); SB0(); } while (0)
#define PRIO_OFF() do { SB0(); __builtin_amdgcn_s_setprio(0); } while (0)
#define VM6() asm volatile("s_waitcnt vmcnt(6)" ::: "memory")
#define VM4() asm volatile("s_waitcnt vmcnt(4)" ::: "memory")
#define VM0() asm volatile("s_waitcnt vmcnt(0)" ::: "memory")
#define VNOP() ((void)0)

// One K-tile, 4 phases, reads 8/4/8/4. CURB = this tile's preloaded B(n0)
// fragments; NXTB receives next tile's at P4 (PREB). Stages: A(kt+1)->BUF^1
// at P1/P2, B(kt+2)->BUF at P3/P4. VM3 before P3's closing barrier
// (guarantees B(kt+1) for the P4 preload); VM4 before P4's closing barrier
// (guarantees A(kt+1) for next P1).
#define TILE(KT, BUF, CURB, NXTB, S1, S2, VM3, VM4P, PREB)                     \
  do {                                                                         \
    const int kt_ = (KT);                                                      \
    /* P1: 8 reads */                                                          \
    LDA(BUF, 0);                                                               \
    if (S1) { stage1(gA, (BUF) ^ 1, 0, 0, 0, kt_ + 1);                         \
              stage1(gA, (BUF) ^ 1, 0, 0, 1, kt_ + 1); }                       \
    SB0(); BAR(); SB0();                                                       \
    LGKM0();                                                                   \
    PRIO_ON(); MFMAQ(0, CURB, 0); PRIO_OFF();                                  \
    SB0(); BAR(); SB0();                                                       \
    /* P2: 4 reads */                                                          \
    LDB(BUF, b1, 1);                                                           \
    if (S1) { stage1(gA, (BUF) ^ 1, 0, 1, 0, kt_ + 1);                         \
              stage1(gA, (BUF) ^ 1, 0, 1, 1, kt_ + 1); }                       \
    SB0(); BAR(); SB0();                                                       \
    LGKM0();                                                                   \
    PRIO_ON(); MFMAQ(0, b1, 1); PRIO_OFF();                                    \
    SB0(); BAR(); SB0();                                                       \
    /* P3: 8 reads */                                                          \
    LDA(BUF, 1);                                                               \
    if (S2) { stage1(gB, (BUF), 1, 0, 0, kt_ + 2);                             \
              stage1(gB, (BUF), 1, 0, 1, kt_ + 2); }                           \
    SB0(); BAR(); SB0();                                                       \
    LGKM0();                                                                   \
    PRIO_ON(); MFMAQ(1, b1, 1); PRIO_OFF();                                    \
    SB0(); VM3(); SB0(); BAR(); SB0();                                         \
    /* P4: 4 preload reads of B(kt+1, n-half0) from BUF^1 */                   \
    if (PREB) { LDB((BUF) ^ 1, NXTB, 0); }                                     \
    if (S2) { stage1(gB, (BUF), 1, 1, 0, kt_ + 2);                             \
              stage1(gB, (BUF), 1, 1, 1, kt_ + 2); }                           \
    SB0(); BAR(); SB0();                                                       \
    LGKM0();                                                                   \
    PRIO_ON(); MFMAQ(1, CURB, 0); PRIO_OFF();                                  \
    SB0(); VM4P(); SB0(); BAR(); SB0();                                        \
  } while (0)

  // prologue: A(0) 4, B(0) 4, B(1) 4; vmcnt(4) -> tile0 landed, B(1) in flight
  stage1(gA, 0, 0, 0, 0, 0); stage1(gA, 0, 0, 0, 1, 0);
  stage1(gA, 0, 0, 1, 0, 0); stage1(gA, 0, 0, 1, 1, 0);
  stage1(gB, 0, 1, 0, 0, 0); stage1(gB, 0, 1, 0, 1, 0);
  stage1(gB, 0, 1, 1, 0, 0); stage1(gB, 0, 1, 1, 1, 0);
  stage1(gB, 1, 1, 0, 0, 1); stage1(gB, 1, 1, 0, 1, 1);
  stage1(gB, 1, 1, 1, 0, 1); stage1(gB, 1, 1, 1, 1, 1);
  VM4();
  SB0(); BAR(); SB0();
  LDB(0, b0x, 0);  // preload tile0's B(n0); tile0 P1's lgkm0 covers the wait

#pragma unroll 1
  for (int kt = 0; kt < 62; kt += 2) {
    TILE(kt,     0, b0x, b0y, true, true, VM6, VM4, true);
    TILE(kt + 1, 1, b0y, b0x, true, true, VM6, VM4, true);
  }
  TILE(62, 0, b0x, b0y, true,  true,  VM6,  VM4,  true);
  TILE(63, 1, b0y, b0x, true,  false, VM4,  VM0,  true);
  TILE(64, 0, b0x, b0y, false, false, VNOP, VNOP, false);

  // epilogue: C/D layout col=lane&15, row=(lane>>4)*4+jj
  const int orow = bm * 256 + wr * 128 + ((lane >> 4) << 2);
  const int ocol = bn * 256 + wc * 64 + (lane & 15);
#pragma unroll
  for (int mf = 0; mf < 8; ++mf)
#pragma unroll
    for (int nf = 0; nf < 4; ++nf)
#pragma unroll
      for (int jj = 0; jj < 4; ++jj)
        out[(size_t)(orow + mf * 16 + jj) * N_DIM + ocol + nf * 16] =
            acc[mf][nf][jj];
}

// ---------------------------------------------------------------- launch
extern "C" void kernel_launch(void* const* d_in, const int* in_sizes, int n_in,
                              void* d_out, int out_size, void* d_ws, size_t ws_size,
                              hipStream_t stream) {
  const float* x = (const float*)d_in[0];
  const float* scales = (const float*)d_in[1];
  const float* lora_a = (const float*)d_in[2];
  const float* lora_b = (const float*)d_in[3];
  const int* qweight = (const int*)d_in[4];
  const int* qzeros = (const int*)d_in[5];
  float* out = (float*)d_out;

  unsigned short* Xe = (unsigned short*)d_ws;
  unsigned short* Wt = Xe + (size_t)M_DIM * KP;

  prep_x_kernel<<<M_DIM / 16, 256, 0, stream>>>(x, lora_a, Xe);
  dequant_kernel<<<dim3(N_DIM / 64, K_DIM / 64), 256, 0, stream>>>(qweight, qzeros,
                                                                   scales, Wt);
  lorab_t_kernel<<<N_DIM / 64, 256, 0, stream>>>(lora_b, Wt);
  gemm_kernel<<<dim3((N_DIM / 256) * (M_DIM / 256)), 512, 0, stream>>>(Xe, Wt, out);
}